// Round 11
// baseline (32.522 us; speedup 1.0000x reference)
//
#include <hip/hip_runtime.h>
#include <math.h>

#define B_TOTAL 16384
#define NQ 512
#define NUM 3
#define TOPK 8

// One wave per batch, 4 waves/block, no LDS.
// Fast path (~97.4% of batches): extract exact conf-ranks 0..7 via 8
// consume-and-repeat u64-packed butterflies (key<<32 | 511-n: stable
// smaller-index tie-break, no ballot tail), gather ONLY those 8 pos rows,
// then resolve greedy #2/#3 with two ballots over ranks.
// Fallback (exact, rare): continue iterative greedy from rank 8 using the
// already-consumed key state; accepted-set test uses zero-vector auto-pass,
// mirroring the reference's masked-inf semantics.
__global__ __launch_bounds__(256) void greedy_nms_kernel(
    const float* __restrict__ conf,   // [B, NQ]
    const float* __restrict__ pos,    // [B, NQ, 3]
    float* __restrict__ out)          // [B, NUM, 3]
{
    const int lane = threadIdx.x & 63;
    const int b = (blockIdx.x << 2) | (threadIdx.x >> 6);   // grid*4 == B

    const float* cb = conf + (size_t)b * NQ;
    const float* pb = pos  + (size_t)b * NQ * 3;

    // conf: lane owns elements 8l..8l+7 (two 1KB-coalesced float4 loads)
    const float4* cb4 = reinterpret_cast<const float4*>(cb);
    float4 c0 = cb4[lane * 2 + 0];
    float4 c1 = cb4[lane * 2 + 1];
    // fallback row 0 (wave-uniform broadcast load, one line)
    const float p0x = pb[0], p0y = pb[1], p0z = pb[2];

    // monotone float->u32 keys; key 0 == consumed (inputs have no NaN/-inf)
    unsigned k[8];
    {
        float f[8] = {c0.x, c0.y, c0.z, c0.w, c1.x, c1.y, c1.z, c1.w};
        #pragma unroll
        for (int s = 0; s < 8; ++s) {
            int bi = __float_as_int(f[s]);
            k[s] = (unsigned)bi ^ ((unsigned)(bi >> 31) | 0x80000000u);
        }
    }

    // exact argmax -> packed u64 (hi = key, lo = 511-n); tie -> larger lo
    // -> smaller n, identical to stable argsort(-conf). Then caller decodes.
    auto argmax64 = [&]() -> unsigned long long {
        bool s01 = k[1] > k[0];
        unsigned m01 = s01 ? k[1] : k[0]; int i01 = s01 ? 1 : 0;
        bool s23 = k[3] > k[2];
        unsigned m23 = s23 ? k[3] : k[2]; int i23 = s23 ? 3 : 2;
        bool s45 = k[5] > k[4];
        unsigned m45 = s45 ? k[5] : k[4]; int i45 = s45 ? 5 : 4;
        bool s67 = k[7] > k[6];
        unsigned m67 = s67 ? k[7] : k[6]; int i67 = s67 ? 7 : 6;
        if (m23 > m01) { m01 = m23; i01 = i23; }
        if (m67 > m45) { m45 = m67; i45 = i67; }
        if (m45 > m01) { m01 = m45; i01 = i45; }
        unsigned long long key =
            ((unsigned long long)m01 << 32) |
            (unsigned)(NQ - 1 - ((lane << 3) + i01));
        #pragma unroll
        for (int off = 1; off < 64; off <<= 1) {
            unsigned long long o = __shfl_xor(key, off);
            if (o > key) key = o;
        }
        return key;
    };

    auto consume = [&](int n) {
        const int osl = ((n >> 3) == lane) ? (n & 7) : 8;
        #pragma unroll
        for (int s = 0; s < 8; ++s)
            if (osl == s) k[s] = 0u;
    };

    // ---- extract exact top-8 (order + ties identical to argsort(-conf)) --
    int myw = 0;                       // lane i<8 ends with rank-i index
    #pragma unroll
    for (int i = 0; i < TOPK; ++i) {
        unsigned long long K = argmax64();
        const int n = NQ - 1 - (int)(K & 0x1ffu);
        if (lane == i) myw = n;
        consume(n);
    }

    // ---- gather the 8 candidate rows (lanes >=8 re-fetch row 0) ----
    float cx = pb[myw * 3 + 0];
    float cy = pb[myw * 3 + 1];
    float cz = pb[myw * 3 + 2];

    const float TH  = 0.78539816339744830961f; // pi/4 (f32 == jnp thresh)
    const float CLO = 0.70710478f;             // cos(pi/4) - ~2e-6
    const float CHI = 0.70710878f;             // cos(pi/4) + ~2e-6

    auto pass1 = [&](float ax, float ay, float az,
                     float px, float py, float pz) -> bool {
        float d = fabsf(ax * px + ay * py + az * pz);
        if (d <= CLO) return true;                  // clearly >= pi/4
        if (d >= CHI) return false;                 // clearly <  pi/4
        return acosf(fminf(d, 1.f)) >= TH;          // exact at boundary
    };

    // ---- greedy over ranks via ballots ----
    const float p1x = __shfl(cx, 0), p1y = __shfl(cy, 0), p1z = __shfl(cz, 0);
    unsigned long long ball1 =
        __ballot(pass1(p1x, p1y, p1z, cx, cy, cz)) & 0xFEull;  // ranks 1..7

    float o2x = p0x, o2y = p0y, o2z = p0z;
    float o3x = p0x, o3y = p0y, o3z = p0z;
    bool need_fallback;
    float a1x = 0.f, a1y = 0.f, a1z = 0.f;   // second accepted (0 = auto-pass)
    int count = 1;

    if (ball1 != 0) {
        const int i2 = __ffsll(ball1) - 1;
        const float p2x = __shfl(cx, i2), p2y = __shfl(cy, i2),
                    p2z = __shfl(cz, i2);
        o2x = p2x; o2y = p2y; o2z = p2z;
        a1x = p2x; a1y = p2y; a1z = p2z;
        count = 2;
        unsigned long long ball3 =
            ball1 & __ballot(pass1(p2x, p2y, p2z, cx, cy, cz))
                  & ~((2ull << i2) - 1);
        if (ball3 != 0) {
            const int i3 = __ffsll(ball3) - 1;
            o3x = __shfl(cx, i3); o3y = __shfl(cy, i3); o3z = __shfl(cz, i3);
            need_fallback = false;
        } else {
            need_fallback = true;    // #3 beyond rank 7
        }
    } else {
        need_fallback = true;        // #2 beyond rank 7
    }

    // ---- rare exact fallback: continue iterative greedy from rank 8 ----
    if (need_fallback) {
        #pragma unroll 1
        for (int it = TOPK; it < NQ; ++it) {
            unsigned long long K = argmax64();
            if ((unsigned)(K >> 32) == 0u) break;   // keys exhausted
            const int n = NQ - 1 - (int)(K & 0x1ffu);
            consume(n);
            const float px = pb[n * 3 + 0];         // wave-uniform row load
            const float py = pb[n * 3 + 1];
            const float pz = pb[n * 3 + 2];
            // test vs accepted set {p1, a1}; a1=(0,0,0) auto-passes,
            // mirroring the reference's `where(ar<count, ang, inf)` mask.
            bool add = pass1(p1x, p1y, p1z, px, py, pz) &&
                       pass1(a1x, a1y, a1z, px, py, pz);
            if (add) {
                if (count == 1) {
                    o2x = px; o2y = py; o2z = pz;
                    a1x = px; a1y = py; a1z = pz;
                    count = 2;
                } else {
                    o3x = px; o3y = py; o3z = pz;
                    break;
                }
            }
        }
    }

    if (lane == 0) {
        float* ob = out + (size_t)b * 9;
        ob[0] = p1x; ob[1] = p1y; ob[2] = p1z;
        ob[3] = o2x; ob[4] = o2y; ob[5] = o2z;
        ob[6] = o3x; ob[7] = o3y; ob[8] = o3z;
    }
}

extern "C" void kernel_launch(void* const* d_in, const int* in_sizes, int n_in,
                              void* d_out, int out_size, void* d_ws, size_t ws_size,
                              hipStream_t stream) {
    const float* pred_logits = (const float*)d_in[0]; // [B, NQ, 1]
    const float* pred_pos    = (const float*)d_in[1]; // [B, NQ, 3]
    float* out = (float*)d_out;                       // [B, NUM, 3]

    const int grid = B_TOTAL / 4;                     // 4 waves/block
    greedy_nms_kernel<<<grid, 256, 0, stream>>>(pred_logits, pred_pos, out);
}